// Round 5
// baseline (918.608 us; speedup 1.0000x reference)
//
#include <hip/hip_runtime.h>
#include <cstdint>

typedef unsigned long long u64;
typedef unsigned int u32;

#define B_ 4
#define N_ 3600
#define C_ 16
#define NW_ 57        // ceil(N/64) words of adjacency/valid bitmask
#define NWP_ 64       // padded row stride (u64 words) -> unguarded 64-lane loads
#define NPAD_ 3648    // NW_*64
#define NCK_ 4096     // con-key sort size
#define RPW_ 4        // rows per wave
#define RPB_ 16       // rows per block (4 waves)

// ---------------------------------------------------------------------------
// K1: pure adjacency-bitmask kernel, no LDS (boxes read from L2-resident
// global => 8 blocks/CU instead of 2). 4 rows/wave, 16 rows/block. Each
// row's 57 words accumulate in per-lane registers (lane t holds word t) ->
// one contiguous 512B store per row.
//
// Exact division-free IoU test:
//   round_f32(inter/denom) >= 0.4f  <=>  inter > (0.4f - 2^-26)*denom in f64
//   (exact: 26-bit * 24-bit mantissa product; midpoint ties round-to-even to
//   prev(0.4f) < 0.4f -> false, matching strict '>'). denom==0 => inter==0
//   => false, matching 0/0=NaN >= 0.4 false. Zero-padded boxes => false.
// ---------------------------------------------------------------------------
__global__ __launch_bounds__(256) void k_adj(const float* __restrict__ boxes,
                                             u64* __restrict__ adj) {
#pragma clang fp contract(off)
    const int tid  = threadIdx.x;
    const int lane = tid & 63;
    const int wv   = tid >> 6;
    const int g    = blockIdx.x;                 // 0 .. B*N/16-1
    const int b    = g / (N_ / RPB_);
    const int r0   = (g % (N_ / RPB_)) * RPB_ + wv * RPW_;
    const size_t bN = (size_t)b * N_;

    float4 bi[RPW_];
    float  ai[RPW_];
#pragma unroll
    for (int r = 0; r < RPW_; ++r) {
        const float4 bx = reinterpret_cast<const float4*>(boxes)[bN + r0 + r];
        const float x1 = bx.x - bx.z * 0.5f;   // cx - w/2 (reference op order)
        const float y1 = bx.y - bx.w * 0.5f;
        const float x2 = x1 + bx.z;
        const float y2 = y1 + bx.w;
        bi[r] = make_float4(x1, y1, x2, y2);
        ai[r] = (x2 - x1) * (y2 - y1);
    }
    const double MID = (double)0.4f - 0x1p-26;   // exact

    u64 row[RPW_];
#pragma unroll
    for (int r = 0; r < RPW_; ++r) row[r] = 0ull;

    for (int t = 0; t < NW_; ++t) {
        const int j = t * 64 + lane;
        float4 bj4 = make_float4(0.f, 0.f, 0.f, 0.f);
        if (j < N_) bj4 = reinterpret_cast<const float4*>(boxes)[bN + j];
        const float x1j = bj4.x - bj4.z * 0.5f;
        const float y1j = bj4.y - bj4.w * 0.5f;
        const float x2j = x1j + bj4.z;
        const float y2j = y1j + bj4.w;
        const float ajr = (x2j - x1j) * (y2j - y1j);
#pragma unroll
        for (int r = 0; r < RPW_; ++r) {
            const float ltx = fmaxf(bi[r].x, x1j);
            const float lty = fmaxf(bi[r].y, y1j);
            const float rbx = fminf(bi[r].z, x2j);
            const float rby = fminf(bi[r].w, y2j);
            const float whx = fmaxf(rbx - ltx, 0.0f);
            const float why = fmaxf(rby - lty, 0.0f);
            const float inter = whx * why;
            const float denom = (ai[r] + ajr) - inter;
            const int pred = ((double)inter > MID * (double)denom) && (j != r0 + r);
            const u64 m = __ballot(pred);
            if (lane == t) row[r] = m;     // 2x v_cndmask, no LDS
        }
    }

#pragma unroll
    for (int r = 0; r < RPW_; ++r)
        adj[(bN + r0 + r) * NWP_ + lane] = row[r];     // lanes >= NW_ hold 0
}

// ---------------------------------------------------------------------------
// K2: fused pre-filter -> sorts -> greedy NMS w/ threshold-bitmask sweep ->
// output. One 256-thread block per (b,c).
//
// valid0 = pre ∧ (row_i ∩ K(p_i) = ∅), where pre = (p>=conf)&(p>=con_i)&(p>=0)
// and K(p) = {j : con_j > p} (so p >= adj_con ⟺ p>=0 ∧ row∩K empty).
// K is monotone along the desc-score greedy order -> maintained incrementally
// in per-lane registers (lane w owns word w) from the sorted con list; the
// membership test is a word-AND + ballot on the already-prefetched adj row.
// Non-valid0 pre-candidates keep their myword bit but fail the K-test at
// their turn => never act (exactly the reference greedy). Survivors in greedy
// order == reference's final take_along_axis order (suppressed rows are
// exact zeros; stable ties via idx in key low bits).
// ---------------------------------------------------------------------------
__global__ __launch_bounds__(256) void k_select(const float* __restrict__ pro,
                                                const float* __restrict__ con,
                                                const float* __restrict__ conf,
                                                const u64* __restrict__ adj,
                                                const float* __restrict__ boxes,
                                                const float* __restrict__ scales,
                                                float* __restrict__ out) {
#pragma clang fp contract(off)
    __shared__ u64 keys[NCK_];          // candidate keys: (~pkey)<<32 | idx
    __shared__ u64 conkeys[NCK_];       // con keys:       (~ckey)<<32 | idx
    __shared__ float spro[NPAD_];
    __shared__ u32 slist[NPAD_];        // survivor indices, greedy order
    __shared__ u64 pvm[NW_];
    __shared__ u32 s_T, s_S;
    const int tid  = threadIdx.x;
    const int lane = tid & 63;
    const int wv   = tid >> 6;
    const int bc   = blockIdx.x;
    const int b    = bc / C_, c = bc % C_;
    const size_t bN = (size_t)b * N_;
    const float cf = conf[c];

    if (tid == 0) s_T = 0;
    for (int x = N_ + tid; x < NCK_; x += 256) conkeys[x] = ~0ull;
    __syncthreads();

    // --- phase 1: pre-candidates (keyed, unordered) + con keys + pvm ---
    for (int t = wv; t < NW_; t += 4) {
        const int i = t * 64 + lane;
        int pred = 0;
        float p = 0.f;
        u64 ckey = ~0ull;
        u32 pk = 0;
        if (i < N_) {
            const size_t off = (bN + i) * C_ + c;
            p = pro[off];
            const float cn = con[off];
            pred = (p >= cf) && (p >= cn) && (p >= 0.0f);
            const u32 pb = __float_as_uint(p);
            pk = pb ^ ((pb >> 31) ? 0xFFFFFFFFu : 0x80000000u);
            const u32 cb = __float_as_uint(cn);
            const u32 ck = cb ^ ((cb >> 31) ? 0xFFFFFFFFu : 0x80000000u);
            ckey = (((u64)(~ck)) << 32) | (u32)i;
        }
        spro[t * 64 + lane] = p;
        conkeys[t * 64 + lane] = ckey;     // i>=N slots = ~0 (sort to end)
        const u64 bm = __ballot(pred);
        if (lane == 0) pvm[t] = bm;
        u32 base = 0;
        if (lane == 0 && bm) base = atomicAdd(&s_T, (u32)__popcll(bm));
        base = (u32)__shfl((int)base, 0);
        if (pred) keys[base + (u32)__popcll(bm & ((1ull << lane) - 1ull))] =
            (((u64)(~pk)) << 32) | (u32)i;
    }
    __syncthreads();

    const int T = (int)s_T;
    int P = 2;
    while (P < T) P <<= 1;              // P <= 4096
    for (int x = T + tid; x < P; x += 256) keys[x] = ~0ull;
    __syncthreads();

    // --- phase 2a: bitonic sort candidates (asc => score desc, idx asc) ---
    for (int k = 2; k <= P; k <<= 1) {
        for (int j = k >> 1; j > 0; j >>= 1) {
            for (int t = tid; t < P; t += 256) {
                const int ixj = t ^ j;
                if (ixj > t) {
                    const u64 a = keys[t], bb = keys[ixj];
                    const bool up = ((t & k) == 0);
                    if ((a > bb) == up) { keys[t] = bb; keys[ixj] = a; }
                }
            }
            __syncthreads();
        }
    }
    // --- phase 2b: bitonic sort con keys (asc => con desc) ---
    for (int k = 2; k <= NCK_; k <<= 1) {
        for (int j = k >> 1; j > 0; j >>= 1) {
            for (int t = tid; t < NCK_; t += 256) {
                const int ixj = t ^ j;
                if (ixj > t) {
                    const u64 a = conkeys[t], bb = conkeys[ixj];
                    const bool up = ((t & k) == 0);
                    if ((a > bb) == up) { conkeys[t] = bb; conkeys[ixj] = a; }
                }
            }
            __syncthreads();
        }
    }

    // --- phase 3: greedy suppression with K-sweep (wave 0 only) ---
    if (wv == 0) {
        const u32* k32 = (const u32*)keys;
        const u32* c32 = (const u32*)conkeys;
        u64 myword = (lane < NW_) ? pvm[lane] : 0ull;
        u64 Kw = 0ull;                          // lane w owns K word w
        u32 kLo = k32[2 * lane], kHi = k32[2 * lane + 1];
        u32 cLo = c32[2 * lane], cHi = c32[2 * lane + 1];
        int cbase = 0, cpos = 0;
        u64 rowp[16];
        u32 idxp[16], hkp[16];
#pragma unroll
        for (int d = 0; d < 16; ++d) {
            const u32 idxn = (d < T) ? (u32)__builtin_amdgcn_readlane((int)kLo, d) : 0u;
            idxp[d] = idxn;
            hkp[d]  = (u32)__builtin_amdgcn_readlane((int)kHi, d);
            rowp[d] = adj[(bN + idxn) * NWP_ + lane];
        }
        u32 S = 0;
        for (int k0 = 0; k0 < T; k0 += 16) {
#pragma unroll
            for (int d = 0; d < 16; ++d) {
                const int k = k0 + d;
                const u32 idx  = idxp[d];
                const u32 hk_p = hkp[d];
                const u64 row  = rowp[d];       // load issued 16 iters ago
                // prefetch candidate k+16
                const int kn = k + 16;
                if ((kn & 63) == 0) {
                    kLo = k32[2 * (kn + lane)];
                    kHi = k32[2 * (kn + lane) + 1];
                }
                const u32 idxn = (kn < T) ? (u32)__builtin_amdgcn_readlane((int)kLo, kn & 63) : 0u;
                idxp[d] = idxn;
                hkp[d]  = (u32)__builtin_amdgcn_readlane((int)kHi, kn & 63);
                rowp[d] = adj[(bN + idxn) * NWP_ + lane];
                // advance K: insert all cons with hk_con < hk_p (strict)
                if (k < T) {
                    for (;;) {
                        int slot = cpos - cbase;
                        if (slot == 64) {
                            cbase += 64;
                            cLo = c32[2 * (cbase + lane)];
                            cHi = c32[2 * (cbase + lane) + 1];
                            slot = 0;
                        }
                        const u32 hk_c = (u32)__builtin_amdgcn_readlane((int)cHi, slot);
                        if (hk_c >= hk_p) break;
                        const u64 qb = __ballot((lane >= slot) && (cHi < hk_p));
                        const int n = (int)__popcll(qb);
                        for (int s = 0; s < n; ++s) {
                            const u32 j = (u32)__builtin_amdgcn_readlane((int)cLo, slot + s);
                            if ((int)(j >> 6) == lane) Kw |= 1ull << (j & 63);
                        }
                        cpos += n;
                        if (slot + n < 64) break;     // threshold reached in-block
                    }
                }
                // valid-bit test (scalar readlane, wave-uniform)
                const int  w  = (int)(idx >> 6);
                const u32  lo = (u32)__builtin_amdgcn_readlane((int)(u32)myword, w);
                const u32  hi = (u32)__builtin_amdgcn_readlane((int)(u32)(myword >> 32), w);
                const u32  sel = (idx & 32) ? hi : lo;
                u32 bit = (sel >> (idx & 31)) & 1u;
                // adj-con test: row ∩ K must be empty
                const u64 anyhit = __ballot((row & Kw) != 0ull);
                bit &= (u32)(anyhit == 0ull);
                bit &= (u32)(k < T);
                const u64 bm = bit ? ~0ull : 0ull;
                myword &= ~(row & bm);
                if (lane == 0) slist[bit ? S : (NPAD_ - 1)] = idx;
                S += bit;
            }
        }
        if (lane == 0) s_S = S;
    }
    __syncthreads();

    // --- phase 4: parallel output of survivors in greedy order ---
    const int S = (int)s_S;
    const float s = scales[b];
    for (int r = tid; r < S; r += 256) {
        const int idx = (int)slist[r];
        const float4 bx = reinterpret_cast<const float4*>(boxes)[bN + idx];
        const float scx = bx.x * s, scy = bx.y * s, sw = bx.z * s, sh = bx.w * s;
        float* o = out + ((size_t)bc * N_ + r) * 5;
        o[0] = scx - 0.5f * sw;
        o[1] = scy - 0.5f * sh;
        o[2] = scx + 0.5f * sw;
        o[3] = scy + 0.5f * sh;
        o[4] = spro[idx];
        out[(size_t)B_ * C_ * N_ * 5 + (size_t)bc * N_ + r] = 1.0f;
    }
}

// ---------------------------------------------------------------------------
extern "C" void kernel_launch(void* const* d_in, const int* in_sizes, int n_in,
                              void* d_out, int out_size, void* d_ws, size_t ws_size,
                              hipStream_t stream) {
    const float* pro    = (const float*)d_in[0];   // (B,N,C)
    const float* con    = (const float*)d_in[1];   // (B,N,C)
    const float* boxes  = (const float*)d_in[2];   // (B,N,4)
    const float* scales = (const float*)d_in[3];   // (B,)
    const float* conf   = (const float*)d_in[4];   // (C,)

    u64* adj = (u64*)d_ws;                         // B*N*NWP u64 (7.37 MB)

    hipMemsetAsync(d_out, 0, (size_t)out_size * sizeof(float), stream);
    k_adj   <<<B_ * N_ / RPB_, 256, 0, stream>>>(boxes, adj);
    k_select<<<B_ * C_,        256, 0, stream>>>(pro, con, conf, adj,
                                                 boxes, scales, (float*)d_out);
}

// Round 6
// 222.609 us; speedup vs baseline: 4.1266x; 4.1266x over previous
//
#include <hip/hip_runtime.h>
#include <cstdint>

typedef unsigned long long u64;
typedef unsigned int u32;

#define B_ 4
#define N_ 3600
#define C_ 16
#define NW_ 57        // ceil(N/64) words of adjacency/valid bitmask
#define NWP_ 64       // padded row stride (u64 words) -> unguarded 64-lane stores
#define NPAD_ 3648    // NW_*64
#define RPW_ 4        // rows per wave (k_adj)
#define RPB_ 16       // rows per block (k_adj, 4 waves)
#define HW0_ 1856     // j-half 0: words 0..28  (29 words)
#define HW1_ 1792     // j-half 1: words 29..56 (28 words)
#define CH_ 128       // greedy chunk size (candidates per LDS staging round)

// ---------------------------------------------------------------------------
// K1: adjacency bitmask. 4 rows/wave, 16 rows/block; j-range staged in LDS in
// two halves (29.7 KB -> 5 blocks/CU = 20 waves/CU). Lane t holds row word t
// in a register -> one contiguous 512 B store per row (pad lanes store 0).
//
// Exact division-free IoU test:
//   round_f32(inter/denom) >= 0.4f  <=>  inter > (0.4f - 2^-26)*denom in f64
//   (26x24-bit mantissa product is exact; midpoint ties round-to-even to
//   prev(0.4f) < 0.4f -> false, matching strict '>'). denom==0 => inter==0
//   => false, matching 0/0=NaN >= 0.4 false. Zero-padded boxes => false.
// ---------------------------------------------------------------------------
__global__ __launch_bounds__(256, 5) void k_adj(const float* __restrict__ boxes,
                                                u64* __restrict__ adj) {
#pragma clang fp contract(off)
    __shared__ float4 sbox[HW0_];    // (x1,y1,x2,y2), one j-half at a time
    const int tid  = threadIdx.x;
    const int lane = tid & 63;
    const int wv   = tid >> 6;
    const int g    = blockIdx.x;                 // 0 .. B*N/16-1
    const int b    = g / (N_ / RPB_);
    const int r0   = (g % (N_ / RPB_)) * RPB_ + wv * RPW_;
    const size_t bN = (size_t)b * N_;

    float4 bi[RPW_];
    float  ai[RPW_];
#pragma unroll
    for (int r = 0; r < RPW_; ++r) {
        const float4 bx = reinterpret_cast<const float4*>(boxes)[bN + r0 + r];
        const float x1 = bx.x - bx.z * 0.5f;   // cx - w/2 (reference op order)
        const float y1 = bx.y - bx.w * 0.5f;
        const float x2 = x1 + bx.z;
        const float y2 = y1 + bx.w;
        bi[r] = make_float4(x1, y1, x2, y2);
        ai[r] = (x2 - x1) * (y2 - y1);
    }
    const double MID = (double)0.4f - 0x1p-26;   // exact

    u64 row[RPW_];
#pragma unroll
    for (int r = 0; r < RPW_; ++r) row[r] = 0ull;

    int jbase = 0;
    for (int h = 0; h < 2; ++h) {
        const int cnt = h ? HW1_ : HW0_;
        __syncthreads();                         // protect previous half's reads
        for (int jj = tid; jj < cnt; jj += 256) {
            const int j = jbase + jj;
            float x1 = 0.f, y1 = 0.f, x2 = 0.f, y2 = 0.f;
            if (j < N_) {
                const float4 bx = reinterpret_cast<const float4*>(boxes)[bN + j];
                x1 = bx.x - bx.z * 0.5f;
                y1 = bx.y - bx.w * 0.5f;
                x2 = x1 + bx.z;
                y2 = y1 + bx.w;
            }
            sbox[jj] = make_float4(x1, y1, x2, y2);
        }
        __syncthreads();

        const int twn = cnt >> 6;
        for (int tw = 0; tw < twn; ++tw) {
            const int tglob = (jbase >> 6) + tw;
            const int j     = jbase + tw * 64 + lane;
            const float4 bj = sbox[tw * 64 + lane];
            const float ajr = (bj.z - bj.x) * (bj.w - bj.y);
#pragma unroll
            for (int r = 0; r < RPW_; ++r) {
                const float ltx = fmaxf(bi[r].x, bj.x);
                const float lty = fmaxf(bi[r].y, bj.y);
                const float rbx = fminf(bi[r].z, bj.z);
                const float rby = fminf(bi[r].w, bj.w);
                const float whx = fmaxf(rbx - ltx, 0.0f);
                const float why = fmaxf(rby - lty, 0.0f);
                const float inter = whx * why;
                const float denom = (ai[r] + ajr) - inter;
                const int pred = ((double)inter > MID * (double)denom) && (j != r0 + r);
                const u64 m = __ballot(pred);
                if (lane == tglob) row[r] = m;   // 2x v_cndmask
            }
        }
        jbase += cnt;
    }

#pragma unroll
    for (int r = 0; r < RPW_; ++r)
        adj[(bN + r0 + r) * NWP_ + lane] = row[r];     // lanes >= NW_ store 0
}

// ---------------------------------------------------------------------------
// K1b: sparse adj_con. One wave per row: lane w iterates its word's set bits,
// gathers con[j][0..15] (4x float4 from one 64B segment), fmax-accumulates;
// then 6-step shuffle max-reduce. Total work ~ edge count (rows are sparse).
// adj_con init 0 matches reference where(adj, con, 0).
// ---------------------------------------------------------------------------
__global__ __launch_bounds__(256) void k_acon(const u64* __restrict__ adj,
                                              const float* __restrict__ con,
                                              float* __restrict__ adjcon) {
    const int tid  = threadIdx.x;
    const int lane = tid & 63;
    const int wv   = tid >> 6;
    const int g    = blockIdx.x;                 // 0 .. B*N/4-1
    const int b    = g / (N_ / 4);
    const int i    = (g % (N_ / 4)) * 4 + wv;
    const size_t bN = (size_t)b * N_;

    u64 w = adj[(bN + i) * NWP_ + lane];         // pad lanes hold 0

    float cm[C_];
#pragma unroll
    for (int k = 0; k < C_; ++k) cm[k] = 0.0f;

    while (w) {
        const int bit = __builtin_ctzll(w); w &= w - 1;
        const int j   = lane * 64 + bit;
        const float4* cp = reinterpret_cast<const float4*>(con + (bN + j) * C_);
        const float4 c0 = cp[0], c1 = cp[1], c2 = cp[2], c3 = cp[3];
        cm[0]  = fmaxf(cm[0],  c0.x); cm[1]  = fmaxf(cm[1],  c0.y);
        cm[2]  = fmaxf(cm[2],  c0.z); cm[3]  = fmaxf(cm[3],  c0.w);
        cm[4]  = fmaxf(cm[4],  c1.x); cm[5]  = fmaxf(cm[5],  c1.y);
        cm[6]  = fmaxf(cm[6],  c1.z); cm[7]  = fmaxf(cm[7],  c1.w);
        cm[8]  = fmaxf(cm[8],  c2.x); cm[9]  = fmaxf(cm[9],  c2.y);
        cm[10] = fmaxf(cm[10], c2.z); cm[11] = fmaxf(cm[11], c2.w);
        cm[12] = fmaxf(cm[12], c3.x); cm[13] = fmaxf(cm[13], c3.y);
        cm[14] = fmaxf(cm[14], c3.z); cm[15] = fmaxf(cm[15], c3.w);
    }

#pragma unroll
    for (int off = 1; off < 64; off <<= 1) {
#pragma unroll
        for (int k = 0; k < C_; ++k) cm[k] = fmaxf(cm[k], __shfl_xor(cm[k], off));
    }
    if (lane == 0) {
        float4* o = reinterpret_cast<float4*>(adjcon + (bN + i) * C_);
        o[0] = make_float4(cm[0],  cm[1],  cm[2],  cm[3]);
        o[1] = make_float4(cm[4],  cm[5],  cm[6],  cm[7]);
        o[2] = make_float4(cm[8],  cm[9],  cm[10], cm[11]);
        o[3] = make_float4(cm[12], cm[13], cm[14], cm[15]);
    }
}

// ---------------------------------------------------------------------------
// K2: fused valid0 -> compact -> sort -> chunked greedy NMS -> output.
// One 256-thread block per (b,c).
//
// Greedy iterates only valid0 members in score order (exact: suppression only
// clears bits, so non-valid0 boxes never act). Per 128-candidate chunk, all
// 4 waves bulk-stage the adj rows into LDS (independent coalesced loads);
// wave 0 then runs a branch-free serial scan whose only memory dependence is
// a 4-deep prefetched LDS row read. Survivors in greedy order == reference's
// final take_along_axis order (suppressed rows are exact zeros; stable ties
// via idx in key low bits).
// ---------------------------------------------------------------------------
__global__ __launch_bounds__(256) void k_select(const float* __restrict__ pro,
                                                const float* __restrict__ con,
                                                const float* __restrict__ adjcon,
                                                const float* __restrict__ conf,
                                                const u64* __restrict__ adj,
                                                const float* __restrict__ boxes,
                                                const float* __restrict__ scales,
                                                float* __restrict__ out) {
#pragma clang fp contract(off)
    __shared__ u64 keys[4096];           // (~score_bits << 32) | idx (asc sort)
    __shared__ u64 srows[(CH_ + 4) * NW_];
    __shared__ float spro[NPAD_];
    __shared__ u32 slist[NPAD_];         // survivor indices, greedy order
    __shared__ u64 pvm[NW_];
    __shared__ u32 s_T, s_S;
    const int tid  = threadIdx.x;
    const int lane = tid & 63;
    const int wv   = tid >> 6;
    const int bc   = blockIdx.x;
    const int b    = bc / C_, c = bc % C_;
    const size_t bN = (size_t)b * N_;
    const float cf = conf[c];

    if (tid == 0) { s_T = 0; s_S = 0; }
    __syncthreads();

    // --- phase 1: valid0 + unordered keyed compaction (all 4 waves) ---
    for (int t = wv; t < NW_; t += 4) {
        const int i = t * 64 + lane;
        int pred = 0;
        float p = 0.f;
        u32 pk = 0;
        if (i < N_) {
            const size_t off = (bN + i) * C_ + c;
            p = pro[off];
            pred = (p >= cf) && (p >= adjcon[off]) && (p >= con[off]);
            const u32 pb = __float_as_uint(p);
            pk = pb ^ ((pb >> 31) ? 0xFFFFFFFFu : 0x80000000u);
        }
        spro[t * 64 + lane] = p;
        const u64 bm = __ballot(pred);
        if (lane == 0) pvm[t] = bm;
        u32 base = 0;
        if (lane == 0 && bm) base = atomicAdd(&s_T, (u32)__popcll(bm));
        base = (u32)__shfl((int)base, 0);
        if (pred) keys[base + (u32)__popcll(bm & ((1ull << lane) - 1ull))] =
            (((u64)(~pk)) << 32) | (u32)i;
    }
    __syncthreads();

    const int T = (int)s_T;
    int P = 2;
    while (P < T) P <<= 1;               // P <= 4096
    for (int x = T + tid; x < P; x += 256) keys[x] = ~0ull;
    __syncthreads();

    // --- phase 2: bitonic sort (ascending => score desc, idx asc) ---
    for (int k = 2; k <= P; k <<= 1) {
        for (int j = k >> 1; j > 0; j >>= 1) {
            for (int t = tid; t < P; t += 256) {
                const int ixj = t ^ j;
                if (ixj > t) {
                    const u64 a = keys[t], bb = keys[ixj];
                    const bool up = ((t & k) == 0);
                    if ((a > bb) == up) { keys[t] = bb; keys[ixj] = a; }
                }
            }
            __syncthreads();
        }
    }

    // --- phase 3: chunked greedy suppression ---
    const u32* k32 = (const u32*)keys;   // low word of keys[i] = idx
    u64 myword = (lane < NW_) ? pvm[lane] : 0ull;   // meaningful in wave 0
    u32 S = 0;
    for (int c0 = 0; c0 < T; c0 += CH_) {
        const int cn_ = min(CH_, T - c0);
        // stage rows for candidates [c0, c0+cn_) into LDS (all 4 waves)
#pragma unroll 8
        for (int r = wv; r < CH_; r += 4) {
            if (r < cn_) {
                const u32 idx = k32[2 * (c0 + r)];       // LDS broadcast read
                if (lane < NW_)
                    srows[r * NW_ + lane] = adj[(bN + idx) * NWP_ + lane];
            }
        }
        __syncthreads();
        if (wv == 0) {
            const u32 sx0 = (c0 + lane      < T) ? k32[2 * (c0 + lane)]      : 0u;
            const u32 sx1 = (c0 + 64 + lane < T) ? k32[2 * (c0 + 64 + lane)] : 0u;
            u64 rowp[4];
#pragma unroll
            for (int d = 0; d < 4; ++d) rowp[d] = srows[d * NW_ + lane];
            const int cnr = (cn_ + 3) & ~3;
            for (int r4 = 0; r4 < cnr; r4 += 4) {
#pragma unroll
                for (int dd = 0; dd < 4; ++dd) {
                    const int r = r4 + dd;
                    const u32 idx = (u32)__builtin_amdgcn_readlane(
                        (int)((r & 64) ? sx1 : sx0), r & 63);
                    const u64 row = rowp[dd];
                    rowp[dd] = srows[(r + 4) * NW_ + lane];   // 4-deep prefetch
                    const int w  = (int)(idx >> 6);
                    const u32 lo = (u32)__builtin_amdgcn_readlane((int)(u32)myword, w);
                    const u32 hi = (u32)__builtin_amdgcn_readlane((int)(u32)(myword >> 32), w);
                    const u32 sel = (idx & 32) ? hi : lo;
                    u32 bit = (sel >> (idx & 31)) & 1u;
                    bit &= (u32)(r < cn_);
                    const u64 bm = bit ? ~0ull : 0ull;
                    myword &= ~(row & bm);
                    if (lane == 0) slist[bit ? S : (NPAD_ - 1)] = idx;
                    S += bit;
                }
            }
        }
        __syncthreads();
    }
    if (tid == 0) s_S = S;
    __syncthreads();

    // --- phase 4: parallel output of survivors in greedy order ---
    const int Sf = (int)s_S;
    const float s = scales[b];
    for (int r = tid; r < Sf; r += 256) {
        const int idx = (int)slist[r];
        const float4 bx = reinterpret_cast<const float4*>(boxes)[bN + idx];
        const float scx = bx.x * s, scy = bx.y * s, sw = bx.z * s, sh = bx.w * s;
        float* o = out + ((size_t)bc * N_ + r) * 5;
        o[0] = scx - 0.5f * sw;
        o[1] = scy - 0.5f * sh;
        o[2] = scx + 0.5f * sw;
        o[3] = scy + 0.5f * sh;
        o[4] = spro[idx];
        out[(size_t)B_ * C_ * N_ * 5 + (size_t)bc * N_ + r] = 1.0f;
    }
}

// ---------------------------------------------------------------------------
extern "C" void kernel_launch(void* const* d_in, const int* in_sizes, int n_in,
                              void* d_out, int out_size, void* d_ws, size_t ws_size,
                              hipStream_t stream) {
    const float* pro    = (const float*)d_in[0];   // (B,N,C)
    const float* con    = (const float*)d_in[1];   // (B,N,C)
    const float* boxes  = (const float*)d_in[2];   // (B,N,4)
    const float* scales = (const float*)d_in[3];   // (B,)
    const float* conf   = (const float*)d_in[4];   // (C,)

    char* ws = (char*)d_ws;
    u64* adj = (u64*)ws;                                   // B*N*NWP u64 (7.37 MB)
    size_t off = (size_t)B_ * N_ * NWP_ * sizeof(u64);
    float* adjcon = (float*)(ws + off);                    // B*N*C f32   (0.92 MB)

    hipMemsetAsync(d_out, 0, (size_t)out_size * sizeof(float), stream);
    k_adj   <<<B_ * N_ / RPB_, 256, 0, stream>>>(boxes, adj);
    k_acon  <<<B_ * N_ / 4,    256, 0, stream>>>(adj, con, adjcon);
    k_select<<<B_ * C_,        256, 0, stream>>>(pro, con, adjcon, conf, adj,
                                                 boxes, scales, (float*)d_out);
}

// Round 7
// 211.546 us; speedup vs baseline: 4.3424x; 1.0523x over previous
//
#include <hip/hip_runtime.h>
#include <cstdint>

typedef unsigned long long u64;
typedef unsigned int u32;

#define B_ 4
#define N_ 3600
#define C_ 16
#define NW_ 57        // ceil(N/64) words of adjacency/valid bitmask
#define NPAD_ 3648    // NW_*64
#define RPW_ 4        // rows per wave (k_adj)
#define RPB_ 16       // rows per block (k_adj, 4 waves)
#define HW0_ 1856     // j-half 0: words 0..28  (29 words)
#define HW1_ 1792     // j-half 1: words 29..56 (28 words)
#define CH_ 64        // greedy chunk size (candidates per resolution round)

// ---------------------------------------------------------------------------
// K1: adjacency bitmask. 4 rows/wave, 16 rows/block; j-range staged in LDS in
// two halves. Lane t holds row word t in a register -> one contiguous store
// per row (57 words).
//
// Exact division-free IoU test:
//   round_f32(inter/denom) >= 0.4f  <=>  inter > (0.4f - 2^-26)*denom in f64
//   (26x24-bit mantissa product is exact; midpoint ties round-to-even to
//   prev(0.4f) < 0.4f -> false, matching strict '>'). denom==0 => inter==0
//   => false, matching 0/0=NaN >= 0.4 false. Zero-padded boxes => false.
// ---------------------------------------------------------------------------
__global__ __launch_bounds__(256, 5) void k_adj(const float* __restrict__ boxes,
                                                u64* __restrict__ adj) {
#pragma clang fp contract(off)
    __shared__ float4 sbox[HW0_];    // (x1,y1,x2,y2), one j-half at a time
    const int tid  = threadIdx.x;
    const int lane = tid & 63;
    const int wv   = tid >> 6;
    const int g    = blockIdx.x;                 // 0 .. B*N/16-1
    const int b    = g / (N_ / RPB_);
    const int r0   = (g % (N_ / RPB_)) * RPB_ + wv * RPW_;
    const size_t bN = (size_t)b * N_;

    float4 bi[RPW_];
    float  ai[RPW_];
#pragma unroll
    for (int r = 0; r < RPW_; ++r) {
        const float4 bx = reinterpret_cast<const float4*>(boxes)[bN + r0 + r];
        const float x1 = bx.x - bx.z * 0.5f;   // cx - w/2 (reference op order)
        const float y1 = bx.y - bx.w * 0.5f;
        const float x2 = x1 + bx.z;
        const float y2 = y1 + bx.w;
        bi[r] = make_float4(x1, y1, x2, y2);
        ai[r] = (x2 - x1) * (y2 - y1);
    }
    const double MID = (double)0.4f - 0x1p-26;   // exact

    u64 row[RPW_];
#pragma unroll
    for (int r = 0; r < RPW_; ++r) row[r] = 0ull;

    int jbase = 0;
    for (int h = 0; h < 2; ++h) {
        const int cnt = h ? HW1_ : HW0_;
        __syncthreads();                         // protect previous half's reads
        for (int jj = tid; jj < cnt; jj += 256) {
            const int j = jbase + jj;
            float x1 = 0.f, y1 = 0.f, x2 = 0.f, y2 = 0.f;
            if (j < N_) {
                const float4 bx = reinterpret_cast<const float4*>(boxes)[bN + j];
                x1 = bx.x - bx.z * 0.5f;
                y1 = bx.y - bx.w * 0.5f;
                x2 = x1 + bx.z;
                y2 = y1 + bx.w;
            }
            sbox[jj] = make_float4(x1, y1, x2, y2);
        }
        __syncthreads();

        const int twn = cnt >> 6;
        for (int tw = 0; tw < twn; ++tw) {
            const int tglob = (jbase >> 6) + tw;
            const int j     = jbase + tw * 64 + lane;
            const float4 bj = sbox[tw * 64 + lane];
            const float ajr = (bj.z - bj.x) * (bj.w - bj.y);
#pragma unroll
            for (int r = 0; r < RPW_; ++r) {
                const float ltx = fmaxf(bi[r].x, bj.x);
                const float lty = fmaxf(bi[r].y, bj.y);
                const float rbx = fminf(bi[r].z, bj.z);
                const float rby = fminf(bi[r].w, bj.w);
                const float whx = fmaxf(rbx - ltx, 0.0f);
                const float why = fmaxf(rby - lty, 0.0f);
                const float inter = whx * why;
                const float denom = (ai[r] + ajr) - inter;
                const int pred = ((double)inter > MID * (double)denom) && (j != r0 + r);
                const u64 m = __ballot(pred);
                if (lane == tglob) row[r] = m;   // 2x v_cndmask
            }
        }
        jbase += cnt;
    }

#pragma unroll
    for (int r = 0; r < RPW_; ++r)
        if (lane < NW_) adj[(bN + r0 + r) * (size_t)NW_ + lane] = row[r];
}

// ---------------------------------------------------------------------------
// K1b: sparse threshold kernel. One wave per row: lane w iterates its adj
// word's set bits, gathers con[j][0..15], fmax-accumulates; 6-step shuffle
// max-reduce; then thr[i][c] = max(adj_con, con_i) (exact: p>=a && p>=b
// <=> p >= fmax(a,b) for non-NaN inputs; adj_con init 0 matches reference
// where(adj, con, 0) and subsumes p>=0).
// ---------------------------------------------------------------------------
__global__ __launch_bounds__(256) void k_acon(const u64* __restrict__ adj,
                                              const float* __restrict__ con,
                                              float* __restrict__ thr) {
    const int tid  = threadIdx.x;
    const int lane = tid & 63;
    const int wv   = tid >> 6;
    const int g    = blockIdx.x;                 // 0 .. B*N/4-1
    const int b    = g / (N_ / 4);
    const int i    = (g % (N_ / 4)) * 4 + wv;
    const size_t bN = (size_t)b * N_;

    u64 w = (lane < NW_) ? adj[(bN + i) * (size_t)NW_ + lane] : 0ull;

    float cm[C_];
#pragma unroll
    for (int k = 0; k < C_; ++k) cm[k] = 0.0f;

    while (w) {
        const int bit = __builtin_ctzll(w); w &= w - 1;
        const int j   = lane * 64 + bit;
        const float4* cp = reinterpret_cast<const float4*>(con + (bN + j) * C_);
        const float4 c0 = cp[0], c1 = cp[1], c2 = cp[2], c3 = cp[3];
        cm[0]  = fmaxf(cm[0],  c0.x); cm[1]  = fmaxf(cm[1],  c0.y);
        cm[2]  = fmaxf(cm[2],  c0.z); cm[3]  = fmaxf(cm[3],  c0.w);
        cm[4]  = fmaxf(cm[4],  c1.x); cm[5]  = fmaxf(cm[5],  c1.y);
        cm[6]  = fmaxf(cm[6],  c1.z); cm[7]  = fmaxf(cm[7],  c1.w);
        cm[8]  = fmaxf(cm[8],  c2.x); cm[9]  = fmaxf(cm[9],  c2.y);
        cm[10] = fmaxf(cm[10], c2.z); cm[11] = fmaxf(cm[11], c2.w);
        cm[12] = fmaxf(cm[12], c3.x); cm[13] = fmaxf(cm[13], c3.y);
        cm[14] = fmaxf(cm[14], c3.z); cm[15] = fmaxf(cm[15], c3.w);
    }

#pragma unroll
    for (int off = 1; off < 64; off <<= 1) {
#pragma unroll
        for (int k = 0; k < C_; ++k) cm[k] = fmaxf(cm[k], __shfl_xor(cm[k], off));
    }
    if (lane == 0) {
        const float4* cp = reinterpret_cast<const float4*>(con + (bN + i) * C_);
        const float4 c0 = cp[0], c1 = cp[1], c2 = cp[2], c3 = cp[3];
        float4* o = reinterpret_cast<float4*>(thr + (bN + i) * C_);
        o[0] = make_float4(fmaxf(cm[0],  c0.x), fmaxf(cm[1],  c0.y),
                           fmaxf(cm[2],  c0.z), fmaxf(cm[3],  c0.w));
        o[1] = make_float4(fmaxf(cm[4],  c1.x), fmaxf(cm[5],  c1.y),
                           fmaxf(cm[6],  c1.z), fmaxf(cm[7],  c1.w));
        o[2] = make_float4(fmaxf(cm[8],  c2.x), fmaxf(cm[9],  c2.y),
                           fmaxf(cm[10], c2.z), fmaxf(cm[11], c2.w));
        o[3] = make_float4(fmaxf(cm[12], c3.x), fmaxf(cm[13], c3.y),
                           fmaxf(cm[14], c3.z), fmaxf(cm[15], c3.w));
    }
}

// ---------------------------------------------------------------------------
// K2a: valid0 + compaction + bitonic sort per (b,c). Writes sorted candidate
// indices (score desc, idx asc — stable == argsort(-scores)), valid0 ballots,
// and the count to workspace.
// ---------------------------------------------------------------------------
__global__ __launch_bounds__(256) void k_prep(const float* __restrict__ pro,
                                              const float* __restrict__ thr,
                                              const float* __restrict__ conf,
                                              u32* __restrict__ sidx_ws,
                                              u64* __restrict__ pvm_ws,
                                              u32* __restrict__ tcnt) {
    __shared__ u64 keys[4096];           // (~score_bits << 32) | idx (asc sort)
    __shared__ u32 s_T;
    const int tid  = threadIdx.x;
    const int lane = tid & 63;
    const int wv   = tid >> 6;
    const int bc   = blockIdx.x;
    const int b    = bc / C_, c = bc % C_;
    const size_t bN = (size_t)b * N_;
    const float cf = conf[c];

    if (tid == 0) s_T = 0;
    __syncthreads();

    for (int t = wv; t < NW_; t += 4) {
        const int i = t * 64 + lane;
        int pred = 0;
        u32 pk = 0;
        if (i < N_) {
            const size_t off = (bN + i) * C_ + c;
            const float p = pro[off];
            pred = (p >= cf) && (p >= thr[off]);
            const u32 pb = __float_as_uint(p);
            pk = pb ^ ((pb >> 31) ? 0xFFFFFFFFu : 0x80000000u);
        }
        const u64 bm = __ballot(pred);
        if (lane == 0) pvm_ws[(size_t)bc * 64 + t] = bm;
        u32 base = 0;
        if (lane == 0 && bm) base = atomicAdd(&s_T, (u32)__popcll(bm));
        base = (u32)__shfl((int)base, 0);
        if (pred) keys[base + (u32)__popcll(bm & ((1ull << lane) - 1ull))] =
            (((u64)(~pk)) << 32) | (u32)i;
    }
    __syncthreads();

    const int T = (int)s_T;
    int P = 2;
    while (P < T) P <<= 1;               // P <= 4096
    for (int x = T + tid; x < P; x += 256) keys[x] = ~0ull;
    __syncthreads();

    for (int k = 2; k <= P; k <<= 1) {
        for (int j = k >> 1; j > 0; j >>= 1) {
            for (int t = tid; t < P; t += 256) {
                const int ixj = t ^ j;
                if (ixj > t) {
                    const u64 a = keys[t], bb = keys[ixj];
                    const bool up = ((t & k) == 0);
                    if ((a > bb) == up) { keys[t] = bb; keys[ixj] = a; }
                }
            }
            __syncthreads();
        }
    }

    for (int x = tid; x < T; x += 256)
        sidx_ws[(size_t)bc * N_ + x] = (u32)(keys[x] & 0xFFFFFFFFull);
    if (tid == 0) tcnt[bc] = (u32)T;
}

// ---------------------------------------------------------------------------
// K2b: chunk-parallel greedy NMS + output. One 256-thread block per (b,c).
// Per 64-candidate chunk:
//   - all waves: precompute intra-chunk suppression masks (ballot per row),
//     and prefetch next chunk's adj rows into registers (double-buffered LDS)
//   - wave 0: one ballot for external validity bits, then a 64-step pure-
//     scalar greedy resolution (bit -> andn2 chain, ~6 cyc/step), then apply
//     only the accepted rows to the global valid bitmask.
// Exactness: candidate r is accepted iff valid at its turn under (a) prior
// chunks' accepted suppressions (ext bits) and (b) earlier accepted rows in
// this chunk (intra masks) — precisely the reference greedy restricted to
// valid0 members (non-members can never act since valid only shrinks).
// Survivors in greedy order == reference's final sorted output (suppressed
// rows are exact zeros; stable ties).
// ---------------------------------------------------------------------------
__global__ __launch_bounds__(256) void k_greedy(const u32* __restrict__ sidx_ws,
                                                const u64* __restrict__ pvm_ws,
                                                const u32* __restrict__ tcnt,
                                                const u64* __restrict__ adj,
                                                const float* __restrict__ pro,
                                                const float* __restrict__ boxes,
                                                const float* __restrict__ scales,
                                                float* __restrict__ out) {
#pragma clang fp contract(off)
    __shared__ u32 sidx[NPAD_];
    __shared__ u64 srows[2][CH_][NW_];
    __shared__ u64 sintra[CH_];
    __shared__ u32 slist[NPAD_];
    __shared__ u32 s_S;
    const int tid  = threadIdx.x;
    const int lane = tid & 63;
    const int wv   = tid >> 6;
    const int bc   = blockIdx.x;
    const int b    = bc / C_, c = bc % C_;
    const size_t bN = (size_t)b * N_;

    const int T = (int)tcnt[bc];
    for (int x = tid; x < T; x += 256) sidx[x] = sidx_ws[(size_t)bc * N_ + x];
    u64 myword = (lane < NW_) ? pvm_ws[(size_t)bc * 64 + lane] : 0ull;
    __syncthreads();

    // stage chunk 0
    for (int rr = 0; rr < 16; ++rr) {
        const int r = wv * 16 + rr;
        const u32 idx = (r < T) ? sidx[r] : 0u;
        if (lane < NW_) srows[0][r][lane] = adj[(bN + idx) * (size_t)NW_ + lane];
    }
    __syncthreads();

    u32 S = 0;
    const int NCH = (T + CH_ - 1) / CH_;
    for (int ch = 0; ch < NCH; ++ch) {
        const int cur = ch & 1, nxt = cur ^ 1;
        const int c0 = ch * CH_;
        const int cn = min(CH_, T - c0);
        // this lane's candidate of the chunk
        const u32 idxme = (c0 + lane < T) ? sidx[c0 + lane] : 0u;
        const int wme = min((int)(idxme >> 6), NW_ - 1);
        const int bme = (int)(idxme & 63u);
        // prefetch next chunk's rows (issued early, used after wave0 section)
        const int havenext = (ch + 1 < NCH);
        u64 pre[16];
#pragma unroll
        for (int rr = 0; rr < 16; ++rr) {
            const int r = wv * 16 + rr;
            const int q = c0 + CH_ + r;
            const u32 idxn = (havenext && q < T) ? sidx[q] : 0u;
            pre[rr] = (havenext && lane < NW_)
                        ? adj[(bN + idxn) * (size_t)NW_ + lane] : 0ull;
        }
        // intra-chunk masks: sintra[r] bit j = row_r suppresses candidate j
        for (int rr = 0; rr < 16; ++rr) {
            const int r = wv * 16 + rr;
            const u64 rw = srows[cur][r][wme];          // per-lane gather
            const u64 ib = __ballot((lane < cn) && ((rw >> bme) & 1ull));
            if (lane == 0) sintra[r] = ib;
        }
        __syncthreads();
        if (wv == 0) {
            // external validity bits for the chunk (one ballot)
            const u32 mlo = (u32)__shfl((int)(u32)myword, wme);
            const u32 mhi = (u32)__shfl((int)(u32)(myword >> 32), wme);
            const u64 mw  = ((u64)mhi << 32) | mlo;
            u64 cv = __ballot((lane < cn) && ((mw >> bme) & 1ull));
            // per-lane copy of intra masks for readlane access
            const u64 iv = sintra[lane];
            const u32 ivLo = (u32)iv, ivHi = (u32)(iv >> 32);
            // 64-step scalar greedy resolution
            u64 accept = 0ull;
            for (int r = 0; r < CH_; ++r) {
                const u64 bit = (cv >> r) & 1ull;
                const u64 ir  = ((u64)(u32)__builtin_amdgcn_readlane((int)ivHi, r) << 32)
                              |  (u64)(u32)__builtin_amdgcn_readlane((int)ivLo, r);
                cv &= ~(ir & (0ull - bit));
                accept |= bit << r;
            }
            // apply accepted rows to the global valid bitmask
            u64 acc = 0ull, tmp = accept;
            while (tmp) {
                const int r2 = __builtin_ctzll(tmp); tmp &= tmp - 1;
                acc |= srows[cur][r2][min(lane, NW_ - 1)];
            }
            if (lane >= NW_) acc = 0ull;
            myword &= ~acc;
            // emit survivors (greedy order)
            const u32 bitl = (u32)((accept >> lane) & 1ull);
            if (bitl) {
                const u32 pos = S + (u32)__popcll(accept & ((1ull << lane) - 1ull));
                slist[pos] = idxme;
            }
            S += (u32)__popcll(accept);
        }
        // write prefetched rows into the other buffer
        if (havenext) {
#pragma unroll
            for (int rr = 0; rr < 16; ++rr) {
                const int r = wv * 16 + rr;
                if (lane < NW_) srows[nxt][r][lane] = pre[rr];
            }
        }
        __syncthreads();
    }
    if (tid == 0) s_S = S;
    __syncthreads();

    // output survivors in greedy order (suppressed rows stay exact zeros)
    const int Sf = (int)s_S;
    const float s = scales[b];
    for (int r = tid; r < Sf; r += 256) {
        const int idx = (int)slist[r];
        const float4 bx = reinterpret_cast<const float4*>(boxes)[bN + idx];
        const float scx = bx.x * s, scy = bx.y * s, sw = bx.z * s, sh = bx.w * s;
        float* o = out + ((size_t)bc * N_ + r) * 5;
        o[0] = scx - 0.5f * sw;
        o[1] = scy - 0.5f * sh;
        o[2] = scx + 0.5f * sw;
        o[3] = scy + 0.5f * sh;
        o[4] = pro[(bN + idx) * C_ + c];
        out[(size_t)B_ * C_ * N_ * 5 + (size_t)bc * N_ + r] = 1.0f;
    }
}

// ---------------------------------------------------------------------------
extern "C" void kernel_launch(void* const* d_in, const int* in_sizes, int n_in,
                              void* d_out, int out_size, void* d_ws, size_t ws_size,
                              hipStream_t stream) {
    const float* pro    = (const float*)d_in[0];   // (B,N,C)
    const float* con    = (const float*)d_in[1];   // (B,N,C)
    const float* boxes  = (const float*)d_in[2];   // (B,N,4)
    const float* scales = (const float*)d_in[3];   // (B,)
    const float* conf   = (const float*)d_in[4];   // (C,)

    char* ws = (char*)d_ws;
    u64* adj = (u64*)ws;                                   // B*N*NW u64  (6.57 MB)
    size_t off = (size_t)B_ * N_ * NW_ * sizeof(u64);
    float* thr = (float*)(ws + off);                       // B*N*C f32   (0.92 MB)
    off += (size_t)B_ * N_ * C_ * sizeof(float);
    u32* sidx_ws = (u32*)(ws + off);                       // B*C*N u32   (0.92 MB)
    off += (size_t)B_ * C_ * N_ * sizeof(u32);
    u64* pvm_ws = (u64*)(ws + off);                        // 64*64 u64   (32 KB)
    off += (size_t)B_ * C_ * 64 * sizeof(u64);
    u32* tcnt = (u32*)(ws + off);                          // 64 u32

    hipMemsetAsync(d_out, 0, (size_t)out_size * sizeof(float), stream);
    k_adj   <<<B_ * N_ / RPB_, 256, 0, stream>>>(boxes, adj);
    k_acon  <<<B_ * N_ / 4,    256, 0, stream>>>(adj, con, thr);
    k_prep  <<<B_ * C_,        256, 0, stream>>>(pro, thr, conf, sidx_ws, pvm_ws, tcnt);
    k_greedy<<<B_ * C_,        256, 0, stream>>>(sidx_ws, pvm_ws, tcnt, adj, pro,
                                                 boxes, scales, (float*)d_out);
}

// Round 8
// 202.769 us; speedup vs baseline: 4.5303x; 1.0433x over previous
//
#include <hip/hip_runtime.h>
#include <cstdint>

typedef unsigned long long u64;
typedef unsigned int u32;

#define B_ 4
#define N_ 3600
#define C_ 16
#define NW_ 57        // ceil(N/64) words of adjacency/valid bitmask
#define NPAD_ 3648    // NW_*64
#define RPW_ 4        // rows per wave (k_adj)
#define RPB_ 16       // rows per block (k_adj, 4 waves)
#define HW0_ 1856     // j-half 0: words 0..28  (29 words)
#define HW1_ 1792     // j-half 1: words 29..56 (28 words)
#define CH_ 64        // greedy chunk size (candidates per resolution round)

// ---------------------------------------------------------------------------
// K1: adjacency bitmask. 4 rows/wave, 16 rows/block; j-range staged in LDS in
// two halves. Lane t holds row word t in a register -> one contiguous store
// per row (57 words).
//
// Exact division-free IoU test:
//   round_f32(inter/denom) >= 0.4f  <=>  inter > (0.4f - 2^-26)*denom in f64
//   (26x24-bit mantissa product is exact; midpoint ties round-to-even to
//   prev(0.4f) < 0.4f -> false, matching strict '>'). denom==0 => inter==0
//   => false, matching 0/0=NaN >= 0.4 false. Zero-padded boxes => false.
// ---------------------------------------------------------------------------
__global__ __launch_bounds__(256, 5) void k_adj(const float* __restrict__ boxes,
                                                u64* __restrict__ adj) {
#pragma clang fp contract(off)
    __shared__ float4 sbox[HW0_];    // (x1,y1,x2,y2), one j-half at a time
    const int tid  = threadIdx.x;
    const int lane = tid & 63;
    const int wv   = tid >> 6;
    const int g    = blockIdx.x;                 // 0 .. B*N/16-1
    const int b    = g / (N_ / RPB_);
    const int r0   = (g % (N_ / RPB_)) * RPB_ + wv * RPW_;
    const size_t bN = (size_t)b * N_;

    float4 bi[RPW_];
    float  ai[RPW_];
#pragma unroll
    for (int r = 0; r < RPW_; ++r) {
        const float4 bx = reinterpret_cast<const float4*>(boxes)[bN + r0 + r];
        const float x1 = bx.x - bx.z * 0.5f;   // cx - w/2 (reference op order)
        const float y1 = bx.y - bx.w * 0.5f;
        const float x2 = x1 + bx.z;
        const float y2 = y1 + bx.w;
        bi[r] = make_float4(x1, y1, x2, y2);
        ai[r] = (x2 - x1) * (y2 - y1);
    }
    const double MID = (double)0.4f - 0x1p-26;   // exact

    u64 row[RPW_];
#pragma unroll
    for (int r = 0; r < RPW_; ++r) row[r] = 0ull;

    int jbase = 0;
    for (int h = 0; h < 2; ++h) {
        const int cnt = h ? HW1_ : HW0_;
        __syncthreads();                         // protect previous half's reads
        for (int jj = tid; jj < cnt; jj += 256) {
            const int j = jbase + jj;
            float x1 = 0.f, y1 = 0.f, x2 = 0.f, y2 = 0.f;
            if (j < N_) {
                const float4 bx = reinterpret_cast<const float4*>(boxes)[bN + j];
                x1 = bx.x - bx.z * 0.5f;
                y1 = bx.y - bx.w * 0.5f;
                x2 = x1 + bx.z;
                y2 = y1 + bx.w;
            }
            sbox[jj] = make_float4(x1, y1, x2, y2);
        }
        __syncthreads();

        const int twn = cnt >> 6;
        for (int tw = 0; tw < twn; ++tw) {
            const int tglob = (jbase >> 6) + tw;
            const int j     = jbase + tw * 64 + lane;
            const float4 bj = sbox[tw * 64 + lane];
            const float ajr = (bj.z - bj.x) * (bj.w - bj.y);
#pragma unroll
            for (int r = 0; r < RPW_; ++r) {
                const float ltx = fmaxf(bi[r].x, bj.x);
                const float lty = fmaxf(bi[r].y, bj.y);
                const float rbx = fminf(bi[r].z, bj.z);
                const float rby = fminf(bi[r].w, bj.w);
                const float whx = fmaxf(rbx - ltx, 0.0f);
                const float why = fmaxf(rby - lty, 0.0f);
                const float inter = whx * why;
                const float denom = (ai[r] + ajr) - inter;
                const int pred = ((double)inter > MID * (double)denom) && (j != r0 + r);
                const u64 m = __ballot(pred);
                if (lane == tglob) row[r] = m;   // 2x v_cndmask
            }
        }
        jbase += cnt;
    }

#pragma unroll
    for (int r = 0; r < RPW_; ++r)
        if (lane < NW_) adj[(bN + r0 + r) * (size_t)NW_ + lane] = row[r];
}

// ---------------------------------------------------------------------------
// K1b: sparse threshold kernel. One wave per row: lane w iterates its adj
// word's set bits, gathers con[j][0..15], fmax-accumulates; 6-step shuffle
// max-reduce; then thr[i][c] = max(adj_con, con_i) (exact: p>=a && p>=b
// <=> p >= fmax(a,b) for non-NaN inputs; adj_con init 0 matches reference
// where(adj, con, 0) and subsumes p>=0).
// ---------------------------------------------------------------------------
__global__ __launch_bounds__(256) void k_acon(const u64* __restrict__ adj,
                                              const float* __restrict__ con,
                                              float* __restrict__ thr) {
    const int tid  = threadIdx.x;
    const int lane = tid & 63;
    const int wv   = tid >> 6;
    const int g    = blockIdx.x;                 // 0 .. B*N/4-1
    const int b    = g / (N_ / 4);
    const int i    = (g % (N_ / 4)) * 4 + wv;
    const size_t bN = (size_t)b * N_;

    u64 w = (lane < NW_) ? adj[(bN + i) * (size_t)NW_ + lane] : 0ull;

    float cm[C_];
#pragma unroll
    for (int k = 0; k < C_; ++k) cm[k] = 0.0f;

    while (w) {
        const int bit = __builtin_ctzll(w); w &= w - 1;
        const int j   = lane * 64 + bit;
        const float4* cp = reinterpret_cast<const float4*>(con + (bN + j) * C_);
        const float4 c0 = cp[0], c1 = cp[1], c2 = cp[2], c3 = cp[3];
        cm[0]  = fmaxf(cm[0],  c0.x); cm[1]  = fmaxf(cm[1],  c0.y);
        cm[2]  = fmaxf(cm[2],  c0.z); cm[3]  = fmaxf(cm[3],  c0.w);
        cm[4]  = fmaxf(cm[4],  c1.x); cm[5]  = fmaxf(cm[5],  c1.y);
        cm[6]  = fmaxf(cm[6],  c1.z); cm[7]  = fmaxf(cm[7],  c1.w);
        cm[8]  = fmaxf(cm[8],  c2.x); cm[9]  = fmaxf(cm[9],  c2.y);
        cm[10] = fmaxf(cm[10], c2.z); cm[11] = fmaxf(cm[11], c2.w);
        cm[12] = fmaxf(cm[12], c3.x); cm[13] = fmaxf(cm[13], c3.y);
        cm[14] = fmaxf(cm[14], c3.z); cm[15] = fmaxf(cm[15], c3.w);
    }

#pragma unroll
    for (int off = 1; off < 64; off <<= 1) {
#pragma unroll
        for (int k = 0; k < C_; ++k) cm[k] = fmaxf(cm[k], __shfl_xor(cm[k], off));
    }
    if (lane == 0) {
        const float4* cp = reinterpret_cast<const float4*>(con + (bN + i) * C_);
        const float4 c0 = cp[0], c1 = cp[1], c2 = cp[2], c3 = cp[3];
        float4* o = reinterpret_cast<float4*>(thr + (bN + i) * C_);
        o[0] = make_float4(fmaxf(cm[0],  c0.x), fmaxf(cm[1],  c0.y),
                           fmaxf(cm[2],  c0.z), fmaxf(cm[3],  c0.w));
        o[1] = make_float4(fmaxf(cm[4],  c1.x), fmaxf(cm[5],  c1.y),
                           fmaxf(cm[6],  c1.z), fmaxf(cm[7],  c1.w));
        o[2] = make_float4(fmaxf(cm[8],  c2.x), fmaxf(cm[9],  c2.y),
                           fmaxf(cm[10], c2.z), fmaxf(cm[11], c2.w));
        o[3] = make_float4(fmaxf(cm[12], c3.x), fmaxf(cm[13], c3.y),
                           fmaxf(cm[14], c3.z), fmaxf(cm[15], c3.w));
    }
}

// ---------------------------------------------------------------------------
// K2a: valid0 + compaction + bitonic sort per (b,c). Writes sorted candidate
// indices (score desc, idx asc — stable == argsort(-scores)), valid0 ballots,
// and the count to workspace.
// ---------------------------------------------------------------------------
__global__ __launch_bounds__(256) void k_prep(const float* __restrict__ pro,
                                              const float* __restrict__ thr,
                                              const float* __restrict__ conf,
                                              u32* __restrict__ sidx_ws,
                                              u64* __restrict__ pvm_ws,
                                              u32* __restrict__ tcnt) {
    __shared__ u64 keys[4096];           // (~score_bits << 32) | idx (asc sort)
    __shared__ u32 s_T;
    const int tid  = threadIdx.x;
    const int lane = tid & 63;
    const int wv   = tid >> 6;
    const int bc   = blockIdx.x;
    const int b    = bc / C_, c = bc % C_;
    const size_t bN = (size_t)b * N_;
    const float cf = conf[c];

    if (tid == 0) s_T = 0;
    __syncthreads();

    for (int t = wv; t < NW_; t += 4) {
        const int i = t * 64 + lane;
        int pred = 0;
        u32 pk = 0;
        if (i < N_) {
            const size_t off = (bN + i) * C_ + c;
            const float p = pro[off];
            pred = (p >= cf) && (p >= thr[off]);
            const u32 pb = __float_as_uint(p);
            pk = pb ^ ((pb >> 31) ? 0xFFFFFFFFu : 0x80000000u);
        }
        const u64 bm = __ballot(pred);
        if (lane == 0) pvm_ws[(size_t)bc * 64 + t] = bm;
        u32 base = 0;
        if (lane == 0 && bm) base = atomicAdd(&s_T, (u32)__popcll(bm));
        base = (u32)__shfl((int)base, 0);
        if (pred) keys[base + (u32)__popcll(bm & ((1ull << lane) - 1ull))] =
            (((u64)(~pk)) << 32) | (u32)i;
    }
    __syncthreads();

    const int T = (int)s_T;
    int P = 2;
    while (P < T) P <<= 1;               // P <= 4096
    for (int x = T + tid; x < P; x += 256) keys[x] = ~0ull;
    __syncthreads();

    for (int k = 2; k <= P; k <<= 1) {
        for (int j = k >> 1; j > 0; j >>= 1) {
            for (int t = tid; t < P; t += 256) {
                const int ixj = t ^ j;
                if (ixj > t) {
                    const u64 a = keys[t], bb = keys[ixj];
                    const bool up = ((t & k) == 0);
                    if ((a > bb) == up) { keys[t] = bb; keys[ixj] = a; }
                }
            }
            __syncthreads();
        }
    }

    for (int x = tid; x < T; x += 256)
        sidx_ws[(size_t)bc * N_ + x] = (u32)(keys[x] & 0xFFFFFFFFull);
    if (tid == 0) tcnt[bc] = (u32)T;
}

// ---------------------------------------------------------------------------
// K2b: chunk-parallel greedy NMS + output. One 256-thread block per (b,c).
// Valid bitmask lives in LDS (vmask). Per 64-candidate chunk:
//   A (all waves): intra-chunk masks via the SYMMETRY of adjacency
//       (row_r bit idx_j == row_j bit idx_r): lane j reads its own staged
//       row at a wave-uniform word -> one read + ballot per r. Also issues
//       next chunk's row loads into registers (double-buffered LDS).
//   B (wave 0): external validity bits = one LDS scatter read + ballot;
//       SPARSE resolve: while(cv){r=ctz; accept; cv&=~(intra[r]|1<<r);}
//       (steps == accepted count, ~12/chunk); emit survivors to slist.
//   C (all waves): apply accepted rows in parallel (contiguous LDS reads,
//       uniform branches) via atomicAnd into vmask; store prefetched rows.
// Exactness: candidate accepted iff valid at its turn under prior chunks'
// suppressions (vmask) and earlier accepted rows in-chunk (intra) — the
// reference greedy restricted to valid0 members (non-members never act since
// valid only shrinks). Survivors in greedy order == reference output order.
// ---------------------------------------------------------------------------
__global__ __launch_bounds__(256) void k_greedy(const u32* __restrict__ sidx_ws,
                                                const u64* __restrict__ pvm_ws,
                                                const u32* __restrict__ tcnt,
                                                const u64* __restrict__ adj,
                                                const float* __restrict__ pro,
                                                const float* __restrict__ boxes,
                                                const float* __restrict__ scales,
                                                float* __restrict__ out) {
#pragma clang fp contract(off)
    __shared__ u32 sidx[NPAD_];
    __shared__ u64 srows[2][CH_][NW_];
    __shared__ u64 sintra[CH_];
    __shared__ u64 vmask[NW_];
    __shared__ u64 s_accept;
    __shared__ u32 slist[NPAD_];
    __shared__ u32 s_S;
    const int tid  = threadIdx.x;
    const int lane = tid & 63;
    const int wv   = tid >> 6;
    const int bc   = blockIdx.x;
    const int b    = bc / C_, c = bc % C_;
    const size_t bN = (size_t)b * N_;

    const int T = (int)tcnt[bc];
    for (int x = tid; x < T; x += 256) sidx[x] = sidx_ws[(size_t)bc * N_ + x];
    if (tid < NW_) vmask[tid] = pvm_ws[(size_t)bc * 64 + tid];
    __syncthreads();

    // stage chunk 0
#pragma unroll
    for (int rr = 0; rr < 16; ++rr) {
        const int r = wv * 16 + rr;
        const u32 idx = (r < T) ? sidx[r] : 0u;
        if (lane < NW_) srows[0][r][lane] = adj[(bN + idx) * (size_t)NW_ + lane];
    }
    __syncthreads();

    u32 S = 0;                           // meaningful in wave 0
    const int NCH = (T + CH_ - 1) / CH_;
    for (int ch = 0; ch < NCH; ++ch) {
        const int cur = ch & 1, nxt = cur ^ 1;
        const int c0 = ch * CH_;
        const int cn = min(CH_, T - c0);
        const int havenext = (ch + 1 < NCH);

        // --- phase A: prefetch next chunk rows + intra-chunk masks ---
        u64 pre[16];
#pragma unroll
        for (int rr = 0; rr < 16; ++rr) {
            const int r = wv * 16 + rr;
            const int q = c0 + CH_ + r;
            const u32 idxn = (havenext && q < T) ? sidx[q] : 0u;
            pre[rr] = (havenext && lane < NW_)
                        ? adj[(bN + idxn) * (size_t)NW_ + lane] : 0ull;
        }
#pragma unroll
        for (int rr = 0; rr < 16; ++rr) {
            const int r = wv * 16 + rr;
            const u32 idxr = (c0 + r < T) ? sidx[c0 + r] : 0u;   // uniform/iter
            const u64 rj = srows[cur][lane][idxr >> 6];  // own row, sym. trick
            const u64 ib = __ballot((lane < cn) && ((rj >> (idxr & 63)) & 1ull));
            if (lane == 0) sintra[r] = ib;
        }
        __syncthreads();

        // --- phase B: wave 0 sparse resolve + survivor emit ---
        if (wv == 0) {
            const u32 idxme = (c0 + lane < T) ? sidx[c0 + lane] : 0u;
            const u64 vm = vmask[idxme >> 6];            // LDS scatter read
            u64 cv = __ballot((lane < cn) && ((vm >> (idxme & 63)) & 1ull));
            const u64 iv = sintra[lane];
            const u32 ivLo = (u32)iv, ivHi = (u32)(iv >> 32);
            u64 accept = 0ull;
            while (cv) {
                const int r = __builtin_ctzll(cv);
                accept |= 1ull << r;
                const u64 ir =
                    ((u64)(u32)__builtin_amdgcn_readlane((int)ivHi, r) << 32)
                  |  (u64)(u32)__builtin_amdgcn_readlane((int)ivLo, r);
                cv &= ~(ir | (1ull << r));
            }
            if (lane == 0) s_accept = accept;
            const u32 bitl = (u32)((accept >> lane) & 1ull);
            if (bitl) {
                const u32 pos = S + (u32)__popcll(accept & ((1ull << lane) - 1ull));
                slist[pos] = idxme;
            }
            S += (u32)__popcll(accept);
        }
        __syncthreads();

        // --- phase C: parallel apply + store prefetched rows ---
        const u64 ac = s_accept;
        u64 acc = 0ull;
#pragma unroll
        for (int rr = 0; rr < 16; ++rr) {
            const int r = wv * 16 + rr;
            if ((ac >> r) & 1ull)                        // wave-uniform branch
                acc |= srows[cur][r][min(lane, NW_ - 1)];
        }
        if (lane < NW_ && acc)
            atomicAnd(&vmask[lane], ~acc);
        if (havenext) {
#pragma unroll
            for (int rr = 0; rr < 16; ++rr) {
                const int r = wv * 16 + rr;
                if (lane < NW_) srows[nxt][r][lane] = pre[rr];
            }
        }
        __syncthreads();
    }
    if (wv == 0 && lane == 0) s_S = S;
    __syncthreads();

    // output survivors in greedy order (suppressed rows stay exact zeros)
    const int Sf = (int)s_S;
    const float s = scales[b];
    for (int r = tid; r < Sf; r += 256) {
        const int idx = (int)slist[r];
        const float4 bx = reinterpret_cast<const float4*>(boxes)[bN + idx];
        const float scx = bx.x * s, scy = bx.y * s, sw = bx.z * s, sh = bx.w * s;
        float* o = out + ((size_t)bc * N_ + r) * 5;
        o[0] = scx - 0.5f * sw;
        o[1] = scy - 0.5f * sh;
        o[2] = scx + 0.5f * sw;
        o[3] = scy + 0.5f * sh;
        o[4] = pro[(bN + idx) * C_ + c];
        out[(size_t)B_ * C_ * N_ * 5 + (size_t)bc * N_ + r] = 1.0f;
    }
}

// ---------------------------------------------------------------------------
extern "C" void kernel_launch(void* const* d_in, const int* in_sizes, int n_in,
                              void* d_out, int out_size, void* d_ws, size_t ws_size,
                              hipStream_t stream) {
    const float* pro    = (const float*)d_in[0];   // (B,N,C)
    const float* con    = (const float*)d_in[1];   // (B,N,C)
    const float* boxes  = (const float*)d_in[2];   // (B,N,4)
    const float* scales = (const float*)d_in[3];   // (B,)
    const float* conf   = (const float*)d_in[4];   // (C,)

    char* ws = (char*)d_ws;
    u64* adj = (u64*)ws;                                   // B*N*NW u64  (6.57 MB)
    size_t off = (size_t)B_ * N_ * NW_ * sizeof(u64);
    float* thr = (float*)(ws + off);                       // B*N*C f32   (0.92 MB)
    off += (size_t)B_ * N_ * C_ * sizeof(float);
    u32* sidx_ws = (u32*)(ws + off);                       // B*C*N u32   (0.92 MB)
    off += (size_t)B_ * C_ * N_ * sizeof(u32);
    u64* pvm_ws = (u64*)(ws + off);                        // 64*64 u64   (32 KB)
    off += (size_t)B_ * C_ * 64 * sizeof(u64);
    u32* tcnt = (u32*)(ws + off);                          // 64 u32

    hipMemsetAsync(d_out, 0, (size_t)out_size * sizeof(float), stream);
    k_adj   <<<B_ * N_ / RPB_, 256, 0, stream>>>(boxes, adj);
    k_acon  <<<B_ * N_ / 4,    256, 0, stream>>>(adj, con, thr);
    k_prep  <<<B_ * C_,        256, 0, stream>>>(pro, thr, conf, sidx_ws, pvm_ws, tcnt);
    k_greedy<<<B_ * C_,        256, 0, stream>>>(sidx_ws, pvm_ws, tcnt, adj, pro,
                                                 boxes, scales, (float*)d_out);
}